// Round 13
// baseline (1770.744 us; speedup 1.0000x reference)
//
#include <hip/hip_runtime.h>
#include <hip/hip_bf16.h>
#include <math.h>

#define BB 8
#define TT 512
#define CC 512
#define HH 8
#define DH 64
#define LL 2
#define VV 512
#define NSTEPS 4
#define BT (BB*TT)
#define FF (4*CC)

typedef unsigned short u16;
typedef __bf16 bf16x8 __attribute__((ext_vector_type(8)));
typedef float f32x4 __attribute__((ext_vector_type(4)));
typedef u16 u16x8 __attribute__((ext_vector_type(8)));

// fp32 -> bf16 bits, round-to-nearest-even
static __device__ __forceinline__ u16 f2bf(float f) {
    unsigned int u = __float_as_uint(f);
    unsigned int r = (u + 0x7fffu + ((u >> 16) & 1u)) >> 16;
    return (u16)r;
}

// async global->LDS, 16 bytes per lane (global_load_lds_dwordx4) — attention only now
static __device__ __forceinline__ void async16(const void* g, void* l) {
    __builtin_amdgcn_global_load_lds((__attribute__((address_space(1))) void*)g,
                                     (__attribute__((address_space(3))) void*)l, 16, 0, 0);
}

// bank swizzle (attention LDS): row r's global chunk g lives at LDS chunk g ^ p(r).
static __device__ __forceinline__ int swzp(int r) { return (r ^ (r >> 2)) & 7; }

// ---------------- embedding ----------------
__global__ void embed_kernel(const int* __restrict__ idx, const float* __restrict__ tok,
                             const float* __restrict__ pos, float* __restrict__ x) {
    int bt = blockIdx.x;
    int t  = threadIdx.x;
    int token = idx[bt];
    int posrow = bt % TT;
    x[(size_t)bt*CC + t]       = tok[token*CC + t]       + pos[posrow*CC + t];
    x[(size_t)bt*CC + t + 256] = tok[token*CC + t + 256] + pos[posrow*CC + t + 256];
}

// ---------------- layernorm: one WAVE per row, no LDS, no barriers ----------------
__global__ __launch_bounds__(256)
void ln_kernel(const float* __restrict__ x, const float* __restrict__ g,
               const float* __restrict__ b, u16* __restrict__ out) {
    int wid = threadIdx.x >> 6, lane = threadIdx.x & 63;
    int row = blockIdx.x * 4 + wid;
    const float* xr = x + (size_t)row * CC;
    f32x4 v0 = ((const f32x4*)xr)[lane*2];
    f32x4 v1 = ((const f32x4*)xr)[lane*2 + 1];
    float s = 0.f, sq = 0.f;
#pragma unroll
    for (int j = 0; j < 4; j++) {
        s += v0[j] + v1[j];
        sq += v0[j]*v0[j] + v1[j]*v1[j];
    }
#pragma unroll
    for (int off = 1; off < 64; off <<= 1) { s += __shfl_xor(s, off); sq += __shfl_xor(sq, off); }
    float mean = s * (1.0f / CC);
    float var  = sq * (1.0f / CC) - mean * mean;
    float inv  = rsqrtf(var + 1e-5f);
    f32x4 g0 = ((const f32x4*)g)[lane*2], g1 = ((const f32x4*)g)[lane*2 + 1];
    f32x4 b0 = ((const f32x4*)b)[lane*2], b1 = ((const f32x4*)b)[lane*2 + 1];
    u16x8 o;
#pragma unroll
    for (int j = 0; j < 4; j++) o[j]     = f2bf((v0[j] - mean) * inv * g0[j] + b0[j]);
#pragma unroll
    for (int j = 0; j < 4; j++) o[4 + j] = f2bf((v1[j] - mean) * inv * g1[j] + b1[j]);
    *(u16x8*)&out[(size_t)row*CC + lane*8] = o;
}

// ---------------- merged cast+transpose of ALL weights (one launch) ----------------
__global__ __launch_bounds__(256)
void cast_all_kernel(const float* __restrict__ Wq, const float* __restrict__ Wk,
                     const float* __restrict__ Wv, const float* __restrict__ Wp,
                     const float* __restrict__ W1, const float* __restrict__ W2,
                     const float* __restrict__ Wh,
                     u16* w_qkvt, u16* w_pt, u16* w_1t, u16* w_2t, u16* w_ht) {
    int bid = blockIdx.x;
    const float* src; u16* dst; int K, N, i0, j0;
    const size_t wcc = (size_t)CC*CC, wcf = (size_t)CC*FF;
    if (bid < 1536) {
        int l = bid / 768, r = bid % 768;
        if (r < 256) {
            int m = r / 64, t = r % 64;
            K = CC; N = CC;
            i0 = (t / 8) * 64; j0 = (t % 8) * 64;
            if      (m == 0) { src = Wq + l*wcc; dst = w_qkvt + (size_t)l*3*wcc; }
            else if (m == 1) { src = Wk + l*wcc; dst = w_qkvt + (size_t)l*3*wcc + wcc; }
            else if (m == 2) { src = Wv + l*wcc; dst = w_qkvt + (size_t)l*3*wcc + 2*wcc; }
            else             { src = Wp + l*wcc; dst = w_pt + (size_t)l*wcc; }
        } else if (r < 512) {
            int t = r - 256;               // W1: [CC][FF] -> [FF][CC]
            K = CC; N = FF;
            i0 = (t / 32) * 64; j0 = (t % 32) * 64;
            src = W1 + l*wcf; dst = w_1t + (size_t)l*wcf;
        } else {
            int t = r - 512;               // W2: [FF][CC] -> [CC][FF]
            K = FF; N = CC;
            i0 = (t / 8) * 64; j0 = (t % 8) * 64;
            src = W2 + l*wcf; dst = w_2t + (size_t)l*wcf;
        }
    } else {
        int t = bid - 1536;
        K = CC; N = CC;
        i0 = (t / 8) * 64; j0 = (t % 8) * 64;
        src = Wh; dst = w_ht;
    }
    __shared__ float tile[64][65];
    int tt = threadIdx.x;
    int rr = tt >> 2, cg = (tt & 3) * 16;
#pragma unroll
    for (int i = 0; i < 16; i++)
        tile[rr][cg + i] = src[(size_t)(i0 + rr) * N + j0 + cg + i];
    __syncthreads();
#pragma unroll
    for (int i = 0; i < 16; i++)
        dst[(size_t)(j0 + rr) * K + i0 + cg + i] = f2bf(tile[cg + i][rr]);
}

// ---------------- MFMA GEMM, DIRECT-GLOBAL fragments: no LDS, no barriers ----------------
// out = A[M,K](bf16) @ Bt[N,K]^T.  WROWS x WCOLS waves, per-wave (BM/WROWS)x(BN/WCOLS).
// Fragment loads go straight global->VGPR (16 B/lane; a quad's 4x16 B fills whole 64 B
// lines; A/B are L1/L2-resident).  Register-double-buffered K-loop; the compiler
// pipelines with plain vmcnt waits — no __syncthreads barrier-drain (the m97 plateau
// mechanism that capped the LDS-staged versions at ~7% MfmaUtil).
// EPI 0: fused QKV (q pre-scaled by 1/8; v transposed to [B][H][DH][T])
// EPI 1: bias + residual accumulate into fp32 outf
// EPI 2: bias + exact GELU -> bf16 outq
// EPI 3: plain fp32 out
template<int BM, int BN, int WROWS, int WCOLS, int EPI>
__global__ __launch_bounds__(WROWS*WCOLS*64)
void gemm_bt_kernel(const u16* __restrict__ A, const u16* __restrict__ Bt,
                    int N, int K,
                    const float* __restrict__ bias, const float* __restrict__ biask,
                    const float* __restrict__ biasv,
                    float* outf, u16* outq, u16* outk, u16* outvt) {
    constexpr int WTM = BM / WROWS, WTN = BN / WCOLS;
    constexpr int TM = WTM / 16, TN = WTN / 16;
    int tid = threadIdx.x;
    int wid = tid >> 6, lane = tid & 63;
    int quad = lane >> 4, l15 = lane & 15;
    int wm = (wid % WROWS) * WTM, wn = (wid / WROWS) * WTN;

    // XCD swizzle: lin&7 picks bm residue -> all bn-blocks of a bm on one XCD
    int NBN = N / BN;
    int lin = blockIdx.x;
    int x8 = lin & 7, slot = lin >> 3;
    int bn = slot % NBN;
    int bm = (slot / NBN) * 8 + x8;

    const size_t a0 = (size_t)bm * BM, b0 = (size_t)bn * BN;
    const u16* Abase = A  + (a0 + wm + l15) * (size_t)K + quad * 8;
    const u16* Bbase = Bt + (b0 + wn + l15) * (size_t)K + quad * 8;

    f32x4 zero = {0.f, 0.f, 0.f, 0.f};
    f32x4 acc[TM][TN];
#pragma unroll
    for (int mi = 0; mi < TM; mi++)
#pragma unroll
        for (int ni = 0; ni < TN; ni++) acc[mi][ni] = zero;

    bf16x8 afA[TM], bfA[TN], afB[TM], bfB[TN];
    auto loadf = [&](bf16x8* af, bf16x8* bf, int kt) {
#pragma unroll
        for (int mi = 0; mi < TM; mi++)
            af[mi] = *(const bf16x8*)(Abase + (size_t)mi * 16 * K + kt);
#pragma unroll
        for (int ni = 0; ni < TN; ni++)
            bf[ni] = *(const bf16x8*)(Bbase + (size_t)ni * 16 * K + kt);
    };
    auto domfma = [&](bf16x8* af, bf16x8* bf) {
#pragma unroll
        for (int mi = 0; mi < TM; mi++)
#pragma unroll
            for (int ni = 0; ni < TN; ni++)
                acc[mi][ni] = __builtin_amdgcn_mfma_f32_16x16x32_bf16(af[mi], bf[ni], acc[mi][ni], 0, 0, 0);
    };

    loadf(afA, bfA, 0);
    for (int kt = 0; kt < K; kt += 64) {
        loadf(afB, bfB, kt + 32);
        domfma(afA, bfA);
        if (kt + 64 < K) loadf(afA, bfA, kt + 64);
        domfma(afB, bfB);
    }

#pragma unroll
    for (int mi = 0; mi < TM; mi++)
#pragma unroll
        for (int ni = 0; ni < TN; ni++)
#pragma unroll
            for (int i = 0; i < 4; i++) {
                int row = bm*BM + wm + mi*16 + quad*4 + i;
                int col = bn*BN + wn + ni*16 + l15;
                float v = acc[mi][ni][i];
                if (EPI == 0) {
                    int region = col >> 9, cl = col & 511;
                    if (region == 0) {
                        v = (v + bias[cl]) * 0.125f;   // fold 1/sqrt(64) into q
                        outq[(size_t)row*512 + cl] = f2bf(v);
                    } else if (region == 1) {
                        v += biask[cl];
                        outk[(size_t)row*512 + cl] = f2bf(v);
                    } else {
                        v += biasv[cl];
                        int bb = row >> 9, tpos = row & 511, hh = cl >> 6, dh = cl & 63;
                        outvt[(((size_t)(bb*8 + hh)*64 + dh) << 9) + tpos] = f2bf(v);
                    }
                } else if (EPI == 1) {
                    size_t idx2 = (size_t)row * N + col;
                    v += bias[col] + outf[idx2];
                    outf[idx2] = v;
                } else if (EPI == 2) {
                    v += bias[col];
                    v = 0.5f * v * (1.0f + erff(v * 0.70710678118654752f));
                    outq[(size_t)row * N + col] = f2bf(v);
                } else {
                    outf[(size_t)row * N + col] = v;
                }
            }
}

// ---------------- fused MFMA flash attention (64-q-row tiles, dbuf K/V, swizzled) --------
__global__ __launch_bounds__(256)
void attn_mfma_kernel(const u16* __restrict__ q, const u16* __restrict__ k,
                      const u16* __restrict__ vt, u16* __restrict__ y) {
    __shared__ u16 lq[64][64];
    __shared__ u16 lk[2][64][64];
    __shared__ u16 lv[2][64][64];
    __shared__ u16 lp[4][16][72];
    int qt = blockIdx.x, h = blockIdx.y, b = blockIdx.z;
    int tid = threadIdx.x;
    int wid = tid >> 6, lane = tid & 63;
    int quad = lane >> 4, l15 = lane & 15;
    const int sr = tid >> 3;
    const int sc = (tid & 7) * 8;
    const int gsc = (((tid & 7) ^ swzp(sr)) << 3);

    auto stageKV = [&](int buf, int kt) {
#pragma unroll
        for (int c = 0; c < 2; c++) {
            async16(&k[(size_t)(b*TT + kt*64 + c*32 + sr)*CC + h*DH + gsc], &lk[buf][c*32 + sr][sc]);
            async16(&vt[((size_t)((b*HH + h)*DH + c*32 + sr))*TT + kt*64 + gsc], &lv[buf][c*32 + sr][sc]);
        }
    };

#pragma unroll
    for (int c = 0; c < 2; c++)
        async16(&q[(size_t)(b*TT + qt*64 + c*32 + sr)*CC + h*DH + gsc], &lq[c*32 + sr][sc]);
    stageKV(0, 0);
    __syncthreads();

    f32x4 zero = {0.f, 0.f, 0.f, 0.f};
    f32x4 acc_o[4];
    float m_st[4], l_st[4];
#pragma unroll
    for (int i = 0; i < 4; i++) { m_st[i] = -INFINITY; l_st[i] = 0.f; }
#pragma unroll
    for (int ni = 0; ni < 4; ni++) acc_o[ni] = zero;

    const int rowq = wid*16 + l15;
    const int pq = swzp(rowq);

    for (int kt = 0; kt < TT/64; kt++) {
        int cur = kt & 1;
        if (kt + 1 < TT/64) stageKV(cur ^ 1, kt + 1);

        f32x4 s[4];
#pragma unroll
        for (int ni = 0; ni < 4; ni++) s[ni] = zero;
#pragma unroll
        for (int ks = 0; ks < 2; ks++) {
            int lcq = (ks*4 + quad) ^ pq;
            bf16x8 aq = *(const bf16x8*)&lq[rowq][lcq * 8];
            bf16x8 bfr[4];
#pragma unroll
            for (int ni = 0; ni < 4; ni++) {
                int rowk = ni*16 + l15;
                int lck = (ks*4 + quad) ^ swzp(rowk);
                bfr[ni] = *(const bf16x8*)&lk[cur][rowk][lck * 8];
            }
#pragma unroll
            for (int ni = 0; ni < 4; ni++)
                s[ni] = __builtin_amdgcn_mfma_f32_16x16x32_bf16(aq, bfr[ni], s[ni], 0, 0, 0);
        }

#pragma unroll
        for (int i = 0; i < 4; i++) {
            float mx = -INFINITY;
#pragma unroll
            for (int ni = 0; ni < 4; ni++) mx = fmaxf(mx, s[ni][i]);
#pragma unroll
            for (int off = 1; off < 16; off <<= 1) mx = fmaxf(mx, __shfl_xor(mx, off));
            float mn = fmaxf(m_st[i], mx);
            float al = __expf(m_st[i] - mn);
            float rs = 0.f;
#pragma unroll
            for (int ni = 0; ni < 4; ni++) {
                float p = __expf(s[ni][i] - mn);
                s[ni][i] = p;
                rs += p;
            }
#pragma unroll
            for (int off = 1; off < 16; off <<= 1) rs += __shfl_xor(rs, off);
            l_st[i] = l_st[i] * al + rs;
            m_st[i] = mn;
#pragma unroll
            for (int ni = 0; ni < 4; ni++) acc_o[ni][i] *= al;
        }

#pragma unroll
        for (int ni = 0; ni < 4; ni++)
#pragma unroll
            for (int i = 0; i < 4; i++)
                lp[wid][quad*4 + i][ni*16 + l15] = f2bf(s[ni][i]);

#pragma unroll
        for (int ks = 0; ks < 2; ks++) {
            bf16x8 pa = *(const bf16x8*)&lp[wid][l15][ks*32 + quad*8];
            bf16x8 vb[4];
#pragma unroll
            for (int ni = 0; ni < 4; ni++) {
                int rowv = ni*16 + l15;
                int lcv = (ks*4 + quad) ^ swzp(rowv);
                vb[ni] = *(const bf16x8*)&lv[cur][rowv][lcv * 8];
            }
#pragma unroll
            for (int ni = 0; ni < 4; ni++)
                acc_o[ni] = __builtin_amdgcn_mfma_f32_16x16x32_bf16(pa, vb[ni], acc_o[ni], 0, 0, 0);
        }
        __syncthreads();
    }

#pragma unroll
    for (int i = 0; i < 4; i++) {
        float inv = 1.0f / l_st[i];
#pragma unroll
        for (int ni = 0; ni < 4; ni++) {
            int qrow = qt*64 + wid*16 + quad*4 + i;
            int col  = h*DH + ni*16 + l15;
            y[(size_t)(b*TT + qrow)*CC + col] = f2bf(acc_o[ni][i] * inv);
        }
    }
}

extern "C" void kernel_launch(void* const* d_in, const int* in_sizes, int n_in,
                              void* d_out, int out_size, void* d_ws, size_t ws_size,
                              hipStream_t stream) {
    const int*   idx   = (const int*)d_in[0];
    const float* tok   = (const float*)d_in[1];
    const float* pos   = (const float*)d_in[2];
    const float* ln1g  = (const float*)d_in[3];
    const float* ln1b  = (const float*)d_in[4];
    const float* Wq    = (const float*)d_in[5];
    const float* bq    = (const float*)d_in[6];
    const float* Wk    = (const float*)d_in[7];
    const float* bk    = (const float*)d_in[8];
    const float* Wv    = (const float*)d_in[9];
    const float* bv    = (const float*)d_in[10];
    const float* Wp    = (const float*)d_in[11];
    const float* bp    = (const float*)d_in[12];
    const float* ln2g  = (const float*)d_in[13];
    const float* ln2b  = (const float*)d_in[14];
    const float* W1    = (const float*)d_in[15];
    const float* b1    = (const float*)d_in[16];
    const float* W2    = (const float*)d_in[17];
    const float* b2    = (const float*)d_in[18];
    const float* lnfg  = (const float*)d_in[19];
    const float* lnfb  = (const float*)d_in[20];
    const float* Whead = (const float*)d_in[21];

    // ---- workspace layout ----
    float* x  = (float*)d_ws;                       // BT*CC fp32
    u16* xn   = (u16*)(x + (size_t)BT*CC);          // BT*CC bf16
    u16* R    = xn + (size_t)BT*CC;
    u16* qb   = R;
    u16* kb   = R + (size_t)BT*CC;
    u16* vtb  = R + (size_t)2*BT*CC;
    u16* hb   = R;                                  // BT*FF spans region (q/k/vt dead in MLP)
    u16* w_qkvt = R + (size_t)4*BT*CC;
    u16* w_pt   = w_qkvt + (size_t)2*3*CC*CC;
    u16* w_1t   = w_pt   + (size_t)2*CC*CC;
    u16* w_2t   = w_1t   + (size_t)2*CC*FF;
    u16* w_ht   = w_2t   + (size_t)2*FF*CC;

    cast_all_kernel<<<1600, 256, 0, stream>>>(Wq, Wk, Wv, Wp, W1, W2, Whead,
                                              w_qkvt, w_pt, w_1t, w_2t, w_ht);
    embed_kernel<<<BT, 256, 0, stream>>>(idx, tok, pos, x);

    // grids: blocks = (N/BN) * (M/BM)
    const int g_qkv  = (3*CC/128) * (BT/64);   // 12*64  = 768
    const int g_fc1  = (FF/128)   * (BT/64);   // 16*64  = 1024
    const int g_proj = (CC/128)   * (BT/32);   // 4*128  = 512
    const int g_fc2  = (CC/128)   * (BT/32);   // 512
    const int g_head = (VV/128)   * (BT/32);   // 512

    for (int s = 0; s < NSTEPS; s++) {
        for (int l = 0; l < LL; l++) {
            // attention
            ln_kernel<<<BT/4, 256, 0, stream>>>(x, ln1g + l*CC, ln1b + l*CC, xn);
            gemm_bt_kernel<64,128,2,2,0><<<g_qkv, 256, 0, stream>>>(
                xn, w_qkvt + (size_t)l*3*CC*CC, 3*CC, CC,
                bq + l*CC, bk + l*CC, bv + l*CC, nullptr, qb, kb, vtb);
            attn_mfma_kernel<<<dim3(TT/64, HH, BB), 256, 0, stream>>>(qb, kb, vtb, xn);
            gemm_bt_kernel<32,128,1,4,1><<<g_proj, 256, 0, stream>>>(
                xn, w_pt + (size_t)l*CC*CC, CC, CC,
                bp + l*CC, nullptr, nullptr, x, nullptr, nullptr, nullptr);
            // MLP
            ln_kernel<<<BT/4, 256, 0, stream>>>(x, ln2g + l*CC, ln2b + l*CC, xn);
            gemm_bt_kernel<64,128,2,2,2><<<g_fc1, 256, 0, stream>>>(
                xn, w_1t + (size_t)l*CC*FF, FF, CC,
                b1 + (size_t)l*FF, nullptr, nullptr, nullptr, hb, nullptr, nullptr);
            gemm_bt_kernel<32,128,1,4,1><<<g_fc2, 256, 0, stream>>>(
                hb, w_2t + (size_t)l*FF*CC, CC, FF,
                b2 + l*CC, nullptr, nullptr, x, nullptr, nullptr, nullptr);
        }
    }

    // final LN + head (fp32 logits)
    ln_kernel<<<BT/4, 256, 0, stream>>>(x, lnfg, lnfb, xn);
    gemm_bt_kernel<32,128,1,4,3><<<g_head, 256, 0, stream>>>(
        xn, w_ht, VV, CC, nullptr, nullptr, nullptr, (float*)d_out, nullptr, nullptr, nullptr);
}

// Round 14
// 916.436 us; speedup vs baseline: 1.9322x; 1.9322x over previous
//
#include <hip/hip_runtime.h>
#include <hip/hip_bf16.h>
#include <math.h>

#define BB 8
#define TT 512
#define CC 512
#define HH 8
#define DH 64
#define LL 2
#define VV 512
#define NSTEPS 4
#define BT (BB*TT)
#define FF (4*CC)

typedef unsigned short u16;
typedef __bf16 bf16x8 __attribute__((ext_vector_type(8)));
typedef float f32x4 __attribute__((ext_vector_type(4)));
typedef u16 u16x8 __attribute__((ext_vector_type(8)));

// fp32 -> bf16 bits, round-to-nearest-even
static __device__ __forceinline__ u16 f2bf(float f) {
    unsigned int u = __float_as_uint(f);
    unsigned int r = (u + 0x7fffu + ((u >> 16) & 1u)) >> 16;
    return (u16)r;
}

// async global->LDS, 16 bytes per lane (global_load_lds_dwordx4)
static __device__ __forceinline__ void async16(const void* g, void* l) {
    __builtin_amdgcn_global_load_lds((__attribute__((address_space(1))) void*)g,
                                     (__attribute__((address_space(3))) void*)l, 16, 0, 0);
}

// bank swizzle: row r's global chunk g lives at LDS chunk g ^ p(r) (source-side permute).
static __device__ __forceinline__ int swzp(int r) { return (r ^ (r >> 2)) & 7; }

// ---------------- layernorm: one WAVE per row, no LDS, no barriers ----------------
__global__ __launch_bounds__(256)
void ln_kernel(const float* __restrict__ x, const float* __restrict__ g,
               const float* __restrict__ b, u16* __restrict__ out) {
    int wid = threadIdx.x >> 6, lane = threadIdx.x & 63;
    int row = blockIdx.x * 4 + wid;
    const float* xr = x + (size_t)row * CC;
    f32x4 v0 = ((const f32x4*)xr)[lane*2];
    f32x4 v1 = ((const f32x4*)xr)[lane*2 + 1];
    float s = 0.f, sq = 0.f;
#pragma unroll
    for (int j = 0; j < 4; j++) {
        s += v0[j] + v1[j];
        sq += v0[j]*v0[j] + v1[j]*v1[j];
    }
#pragma unroll
    for (int off = 1; off < 64; off <<= 1) { s += __shfl_xor(s, off); sq += __shfl_xor(sq, off); }
    float mean = s * (1.0f / CC);
    float var  = sq * (1.0f / CC) - mean * mean;
    float inv  = rsqrtf(var + 1e-5f);
    f32x4 g0 = ((const f32x4*)g)[lane*2], g1 = ((const f32x4*)g)[lane*2 + 1];
    f32x4 b0 = ((const f32x4*)b)[lane*2], b1 = ((const f32x4*)b)[lane*2 + 1];
    u16x8 o;
#pragma unroll
    for (int j = 0; j < 4; j++) o[j]     = f2bf((v0[j] - mean) * inv * g0[j] + b0[j]);
#pragma unroll
    for (int j = 0; j < 4; j++) o[4 + j] = f2bf((v1[j] - mean) * inv * g1[j] + b1[j]);
    *(u16x8*)&out[(size_t)row*CC + lane*8] = o;
}

// ---------------- merged prologue: cast+transpose ALL weights + embedding (one launch) ----
// blocks 0..1599: weight cast+transpose tiles (fp32 [K][N] -> bf16 [N][K]).
// blocks 1600..5695: embedding rows (x = tok[idx] + pos).
__global__ __launch_bounds__(256)
void prologue_kernel(const float* __restrict__ Wq, const float* __restrict__ Wk,
                     const float* __restrict__ Wv, const float* __restrict__ Wp,
                     const float* __restrict__ W1, const float* __restrict__ W2,
                     const float* __restrict__ Wh,
                     u16* w_qkvt, u16* w_pt, u16* w_1t, u16* w_2t, u16* w_ht,
                     const int* __restrict__ idx, const float* __restrict__ tok,
                     const float* __restrict__ pos, float* __restrict__ x) {
    int bid = blockIdx.x;
    if (bid >= 1600) {
        int bt = bid - 1600;              // 0..4095
        int t  = threadIdx.x;
        int token = idx[bt];
        int posrow = bt % TT;
        x[(size_t)bt*CC + t]       = tok[token*CC + t]       + pos[posrow*CC + t];
        x[(size_t)bt*CC + t + 256] = tok[token*CC + t + 256] + pos[posrow*CC + t + 256];
        return;
    }
    const float* src; u16* dst; int K, N, i0, j0;
    const size_t wcc = (size_t)CC*CC, wcf = (size_t)CC*FF;
    if (bid < 1536) {
        int l = bid / 768, r = bid % 768;
        if (r < 256) {
            int m = r / 64, t = r % 64;
            K = CC; N = CC;
            i0 = (t / 8) * 64; j0 = (t % 8) * 64;
            if      (m == 0) { src = Wq + l*wcc; dst = w_qkvt + (size_t)l*3*wcc; }
            else if (m == 1) { src = Wk + l*wcc; dst = w_qkvt + (size_t)l*3*wcc + wcc; }
            else if (m == 2) { src = Wv + l*wcc; dst = w_qkvt + (size_t)l*3*wcc + 2*wcc; }
            else             { src = Wp + l*wcc; dst = w_pt + (size_t)l*wcc; }
        } else if (r < 512) {
            int t = r - 256;               // W1: [CC][FF] -> [FF][CC]
            K = CC; N = FF;
            i0 = (t / 32) * 64; j0 = (t % 32) * 64;
            src = W1 + l*wcf; dst = w_1t + (size_t)l*wcf;
        } else {
            int t = r - 512;               // W2: [FF][CC] -> [CC][FF]
            K = FF; N = CC;
            i0 = (t / 8) * 64; j0 = (t % 8) * 64;
            src = W2 + l*wcf; dst = w_2t + (size_t)l*wcf;
        }
    } else {
        int t = bid - 1536;
        K = CC; N = CC;
        i0 = (t / 8) * 64; j0 = (t % 8) * 64;
        src = Wh; dst = w_ht;
    }
    __shared__ float tile[64][65];
    int tt = threadIdx.x;
    int rr = tt >> 2, cg = (tt & 3) * 16;
#pragma unroll
    for (int i = 0; i < 16; i++)
        tile[rr][cg + i] = src[(size_t)(i0 + rr) * N + j0 + cg + i];
    __syncthreads();
#pragma unroll
    for (int i = 0; i < 16; i++)
        dst[(size_t)(j0 + rr) * K + i0 + cg + i] = f2bf(tile[cg + i][rr]);
}

// ---------------- MFMA GEMM, dbuf BK=64, bank-swizzled, templated wave grid ----------------
// out = A[M,K](bf16) @ Bt[N,K]^T.  WROWS x WCOLS waves, per-wave (BM/WROWS)x(BN/WCOLS).
// Staging: one A call + B calls per buffer; dest lane-linear (DMA constraint),
// bank swizzle applied on the per-lane GLOBAL source address.
// EPI 0: fused QKV (q pre-scaled by 1/8; v transposed to [B][H][DH][T])
// EPI 1: bias + residual accumulate into fp32 outf
// EPI 2: bias + exact GELU -> bf16 outq
// EPI 3: plain fp32 out
template<int BM, int BN, int THREADS, int WROWS, int WCOLS, int EPI>
__global__ __launch_bounds__(THREADS, 6)
void gemm_bt_kernel(const u16* __restrict__ A, const u16* __restrict__ Bt,
                    int N, int K,
                    const float* __restrict__ bias, const float* __restrict__ biask,
                    const float* __restrict__ biasv,
                    float* outf, u16* outq, u16* outk, u16* outvt) {
    constexpr int WTM = BM / WROWS, WTN = BN / WCOLS;
    constexpr int TM = WTM / 16, TN = WTN / 16;
    static_assert(THREADS / 4 == 2 * BM, "A staged in exactly one call");
    static_assert(THREADS == WROWS * WCOLS * 64, "wave grid");
    __shared__ u16 lds_a[2][2][BM][32];
    __shared__ u16 lds_b[2][2][BN][32];
    int tid = threadIdx.x;
    int wid = tid >> 6, lane = tid & 63;
    int quad = lane >> 4, l15 = lane & 15;
    int wm = (wid % WROWS) * WTM, wn = (wid / WROWS) * WTN;

    // XCD swizzle: lin&7 picks bm residue -> all bn-blocks of a bm on one XCD
    int NBN = N / BN;
    int lin = blockIdx.x;
    int x8 = lin & 7, slot = lin >> 3;
    int bn = slot % NBN;
    int bm = (slot / NBN) * 8 + x8;

    const int fr = tid >> 2;      // flat row 0..THREADS/4-1 over [2][BM or BN]
    const int c2 = tid & 3;       // chunk within quad-group
    const size_t a0 = (size_t)bm * BM, b0 = (size_t)bn * BN;

    auto stage = [&](int buf, int kt) {
        {
            int ks2 = fr / BM, row = fr % BM;
            int g = (ks2 * 4 + c2) ^ swzp(row);
            async16(&A[(a0 + row) * K + kt + g * 8], &lds_a[buf][ks2][row][c2 * 8]);
        }
#pragma unroll
        for (int i = 0; i < (2 * BN) / (THREADS / 4); i++) {
            int f = fr + i * (THREADS / 4);
            int ks2 = f / BN, row = f % BN;
            int g = (ks2 * 4 + c2) ^ swzp(row);
            async16(&Bt[(b0 + row) * K + kt + g * 8], &lds_b[buf][ks2][row][c2 * 8]);
        }
    };

    f32x4 zero = {0.f, 0.f, 0.f, 0.f};
    f32x4 acc[TM][TN];
#pragma unroll
    for (int mi = 0; mi < TM; mi++)
#pragma unroll
        for (int ni = 0; ni < TN; ni++) acc[mi][ni] = zero;

    stage(0, 0);
    __syncthreads();
    const int NKT = K / 64;
    for (int kt = 0; kt < NKT; kt++) {
        int cur = kt & 1;
        if (kt + 1 < NKT) stage(cur ^ 1, (kt + 1) * 64);
#pragma unroll
        for (int ks = 0; ks < 2; ks++) {
            bf16x8 af[TM], bfr[TN];
#pragma unroll
            for (int mi = 0; mi < TM; mi++) {
                int row = wm + mi*16 + l15;
                int lc = (ks*4 + quad) ^ swzp(row);
                af[mi] = *(const bf16x8*)&lds_a[cur][lc >> 2][row][(lc & 3) * 8];
            }
#pragma unroll
            for (int ni = 0; ni < TN; ni++) {
                int row = wn + ni*16 + l15;
                int lc = (ks*4 + quad) ^ swzp(row);
                bfr[ni] = *(const bf16x8*)&lds_b[cur][lc >> 2][row][(lc & 3) * 8];
            }
#pragma unroll
            for (int mi = 0; mi < TM; mi++)
#pragma unroll
                for (int ni = 0; ni < TN; ni++)
                    acc[mi][ni] = __builtin_amdgcn_mfma_f32_16x16x32_bf16(af[mi], bfr[ni], acc[mi][ni], 0, 0, 0);
        }
        __syncthreads();
    }

#pragma unroll
    for (int mi = 0; mi < TM; mi++)
#pragma unroll
        for (int ni = 0; ni < TN; ni++)
#pragma unroll
            for (int i = 0; i < 4; i++) {
                int row = bm*BM + wm + mi*16 + quad*4 + i;
                int col = bn*BN + wn + ni*16 + l15;
                float v = acc[mi][ni][i];
                if (EPI == 0) {
                    int region = col >> 9, cl = col & 511;
                    if (region == 0) {
                        v = (v + bias[cl]) * 0.125f;   // fold 1/sqrt(64) into q
                        outq[(size_t)row*512 + cl] = f2bf(v);
                    } else if (region == 1) {
                        v += biask[cl];
                        outk[(size_t)row*512 + cl] = f2bf(v);
                    } else {
                        v += biasv[cl];
                        int bb = row >> 9, tpos = row & 511, hh = cl >> 6, dh = cl & 63;
                        outvt[(((size_t)(bb*8 + hh)*64 + dh) << 9) + tpos] = f2bf(v);
                    }
                } else if (EPI == 1) {
                    size_t idx2 = (size_t)row * N + col;
                    v += bias[col] + outf[idx2];
                    outf[idx2] = v;
                } else if (EPI == 2) {
                    v += bias[col];
                    v = 0.5f * v * (1.0f + erff(v * 0.70710678118654752f));
                    outq[(size_t)row * N + col] = f2bf(v);
                } else {
                    outf[(size_t)row * N + col] = v;
                }
            }
}

// ---------------- fused MFMA flash attention (64-q-row tiles, dbuf K/V, swizzled) --------
__global__ __launch_bounds__(256)
void attn_mfma_kernel(const u16* __restrict__ q, const u16* __restrict__ k,
                      const u16* __restrict__ vt, u16* __restrict__ y) {
    __shared__ u16 lq[64][64];
    __shared__ u16 lk[2][64][64];
    __shared__ u16 lv[2][64][64];
    __shared__ u16 lp[4][16][72];
    int qt = blockIdx.x, h = blockIdx.y, b = blockIdx.z;
    int tid = threadIdx.x;
    int wid = tid >> 6, lane = tid & 63;
    int quad = lane >> 4, l15 = lane & 15;
    const int sr = tid >> 3;
    const int sc = (tid & 7) * 8;
    const int gsc = (((tid & 7) ^ swzp(sr)) << 3);

    auto stageKV = [&](int buf, int kt) {
#pragma unroll
        for (int c = 0; c < 2; c++) {
            async16(&k[(size_t)(b*TT + kt*64 + c*32 + sr)*CC + h*DH + gsc], &lk[buf][c*32 + sr][sc]);
            async16(&vt[((size_t)((b*HH + h)*DH + c*32 + sr))*TT + kt*64 + gsc], &lv[buf][c*32 + sr][sc]);
        }
    };

#pragma unroll
    for (int c = 0; c < 2; c++)
        async16(&q[(size_t)(b*TT + qt*64 + c*32 + sr)*CC + h*DH + gsc], &lq[c*32 + sr][sc]);
    stageKV(0, 0);
    __syncthreads();

    f32x4 zero = {0.f, 0.f, 0.f, 0.f};
    f32x4 acc_o[4];
    float m_st[4], l_st[4];
#pragma unroll
    for (int i = 0; i < 4; i++) { m_st[i] = -INFINITY; l_st[i] = 0.f; }
#pragma unroll
    for (int ni = 0; ni < 4; ni++) acc_o[ni] = zero;

    const int rowq = wid*16 + l15;
    const int pq = swzp(rowq);

    for (int kt = 0; kt < TT/64; kt++) {
        int cur = kt & 1;
        if (kt + 1 < TT/64) stageKV(cur ^ 1, kt + 1);

        f32x4 s[4];
#pragma unroll
        for (int ni = 0; ni < 4; ni++) s[ni] = zero;
#pragma unroll
        for (int ks = 0; ks < 2; ks++) {
            int lcq = (ks*4 + quad) ^ pq;
            bf16x8 aq = *(const bf16x8*)&lq[rowq][lcq * 8];
            bf16x8 bfr[4];
#pragma unroll
            for (int ni = 0; ni < 4; ni++) {
                int rowk = ni*16 + l15;
                int lck = (ks*4 + quad) ^ swzp(rowk);
                bfr[ni] = *(const bf16x8*)&lk[cur][rowk][lck * 8];
            }
#pragma unroll
            for (int ni = 0; ni < 4; ni++)
                s[ni] = __builtin_amdgcn_mfma_f32_16x16x32_bf16(aq, bfr[ni], s[ni], 0, 0, 0);
        }

#pragma unroll
        for (int i = 0; i < 4; i++) {
            float mx = -INFINITY;
#pragma unroll
            for (int ni = 0; ni < 4; ni++) mx = fmaxf(mx, s[ni][i]);
#pragma unroll
            for (int off = 1; off < 16; off <<= 1) mx = fmaxf(mx, __shfl_xor(mx, off));
            float mn = fmaxf(m_st[i], mx);
            float al = __expf(m_st[i] - mn);
            float rs = 0.f;
#pragma unroll
            for (int ni = 0; ni < 4; ni++) {
                float p = __expf(s[ni][i] - mn);
                s[ni][i] = p;
                rs += p;
            }
#pragma unroll
            for (int off = 1; off < 16; off <<= 1) rs += __shfl_xor(rs, off);
            l_st[i] = l_st[i] * al + rs;
            m_st[i] = mn;
#pragma unroll
            for (int ni = 0; ni < 4; ni++) acc_o[ni][i] *= al;
        }

#pragma unroll
        for (int ni = 0; ni < 4; ni++)
#pragma unroll
            for (int i = 0; i < 4; i++)
                lp[wid][quad*4 + i][ni*16 + l15] = f2bf(s[ni][i]);

#pragma unroll
        for (int ks = 0; ks < 2; ks++) {
            bf16x8 pa = *(const bf16x8*)&lp[wid][l15][ks*32 + quad*8];
            bf16x8 vb[4];
#pragma unroll
            for (int ni = 0; ni < 4; ni++) {
                int rowv = ni*16 + l15;
                int lcv = (ks*4 + quad) ^ swzp(rowv);
                vb[ni] = *(const bf16x8*)&lv[cur][rowv][lcv * 8];
            }
#pragma unroll
            for (int ni = 0; ni < 4; ni++)
                acc_o[ni] = __builtin_amdgcn_mfma_f32_16x16x32_bf16(pa, vb[ni], acc_o[ni], 0, 0, 0);
        }
        __syncthreads();
    }

#pragma unroll
    for (int i = 0; i < 4; i++) {
        float inv = 1.0f / l_st[i];
#pragma unroll
        for (int ni = 0; ni < 4; ni++) {
            int qrow = qt*64 + wid*16 + quad*4 + i;
            int col  = h*DH + ni*16 + l15;
            y[(size_t)(b*TT + qrow)*CC + col] = f2bf(acc_o[ni][i] * inv);
        }
    }
}

extern "C" void kernel_launch(void* const* d_in, const int* in_sizes, int n_in,
                              void* d_out, int out_size, void* d_ws, size_t ws_size,
                              hipStream_t stream) {
    const int*   idx   = (const int*)d_in[0];
    const float* tok   = (const float*)d_in[1];
    const float* pos   = (const float*)d_in[2];
    const float* ln1g  = (const float*)d_in[3];
    const float* ln1b  = (const float*)d_in[4];
    const float* Wq    = (const float*)d_in[5];
    const float* bq    = (const float*)d_in[6];
    const float* Wk    = (const float*)d_in[7];
    const float* bk    = (const float*)d_in[8];
    const float* Wv    = (const float*)d_in[9];
    const float* bv    = (const float*)d_in[10];
    const float* Wp    = (const float*)d_in[11];
    const float* bp    = (const float*)d_in[12];
    const float* ln2g  = (const float*)d_in[13];
    const float* ln2b  = (const float*)d_in[14];
    const float* W1    = (const float*)d_in[15];
    const float* b1    = (const float*)d_in[16];
    const float* W2    = (const float*)d_in[17];
    const float* b2    = (const float*)d_in[18];
    const float* lnfg  = (const float*)d_in[19];
    const float* lnfb  = (const float*)d_in[20];
    const float* Whead = (const float*)d_in[21];

    // ---- workspace layout ----
    float* x  = (float*)d_ws;                       // BT*CC fp32
    u16* xn   = (u16*)(x + (size_t)BT*CC);          // BT*CC bf16
    u16* R    = xn + (size_t)BT*CC;
    u16* qb   = R;
    u16* kb   = R + (size_t)BT*CC;
    u16* vtb  = R + (size_t)2*BT*CC;
    u16* hb   = R;                                  // BT*FF spans region (q/k/vt dead in MLP)
    u16* w_qkvt = R + (size_t)4*BT*CC;
    u16* w_pt   = w_qkvt + (size_t)2*3*CC*CC;
    u16* w_1t   = w_pt   + (size_t)2*CC*CC;
    u16* w_2t   = w_1t   + (size_t)2*CC*FF;
    u16* w_ht   = w_2t   + (size_t)2*FF*CC;

    prologue_kernel<<<1600 + BT, 256, 0, stream>>>(Wq, Wk, Wv, Wp, W1, W2, Whead,
                                                   w_qkvt, w_pt, w_1t, w_2t, w_ht,
                                                   idx, tok, pos, x);

    // grids: blocks = (N/BN) * (M/BM)
    const int g_qkv  = (3*CC/128) * (BT/64);   // 12*64  = 768  (512t)
    const int g_fc1  = (FF/128)   * (BT/64);   // 16*64  = 1024 (512t)
    const int g_proj = (CC/64)    * (BT/32);   // 8*128  = 1024 (256t)
    const int g_fc2  = (CC/64)    * (BT/32);   // 1024
    const int g_head = (VV/64)    * (BT/32);   // 1024

    for (int s = 0; s < NSTEPS; s++) {
        for (int l = 0; l < LL; l++) {
            // attention
            ln_kernel<<<BT/4, 256, 0, stream>>>(x, ln1g + l*CC, ln1b + l*CC, xn);
            gemm_bt_kernel<64,128,512,2,4,0><<<g_qkv, 512, 0, stream>>>(
                xn, w_qkvt + (size_t)l*3*CC*CC, 3*CC, CC,
                bq + l*CC, bk + l*CC, bv + l*CC, nullptr, qb, kb, vtb);
            attn_mfma_kernel<<<dim3(TT/64, HH, BB), 256, 0, stream>>>(qb, kb, vtb, xn);
            gemm_bt_kernel<32,64,256,2,2,1><<<g_proj, 256, 0, stream>>>(
                xn, w_pt + (size_t)l*CC*CC, CC, CC,
                bp + l*CC, nullptr, nullptr, x, nullptr, nullptr, nullptr);
            // MLP
            ln_kernel<<<BT/4, 256, 0, stream>>>(x, ln2g + l*CC, ln2b + l*CC, xn);
            gemm_bt_kernel<64,128,512,2,4,2><<<g_fc1, 512, 0, stream>>>(
                xn, w_1t + (size_t)l*CC*FF, FF, CC,
                b1 + (size_t)l*FF, nullptr, nullptr, nullptr, hb, nullptr, nullptr);
            gemm_bt_kernel<32,64,256,2,2,1><<<g_fc2, 256, 0, stream>>>(
                hb, w_2t + (size_t)l*FF*CC, CC, FF,
                b2 + l*CC, nullptr, nullptr, x, nullptr, nullptr, nullptr);
        }
    }

    // final LN + head (fp32 logits)
    ln_kernel<<<BT/4, 256, 0, stream>>>(x, lnfg, lnfb, xn);
    gemm_bt_kernel<32,64,256,2,2,3><<<g_head, 256, 0, stream>>>(
        xn, w_ht, VV, CC, nullptr, nullptr, nullptr, (float*)d_out, nullptr, nullptr, nullptr);
}